// Round 13
// baseline (113.056 us; speedup 1.0000x reference)
//
#include <hip/hip_runtime.h>

#define NNODES 10000
#define NEDGES 4096
#define INF 300
#define OUTF 150
#define EPB 16                      // edges per block
#define NGROUPS (NEDGES / EPB)      // 256
#define SPLITK 5                    // K split over INF; 300/5 = 60
#define KCHUNK (INF / SPLITK)       // 60
#define PHASES 5                    // burst phases of 12 rows
#define PROWS (KCHUNK / PHASES)     // 12 -> 24 burst regs live
#define ETHREADS 192                // lanes 0..149 compute

#define SUMS_N (NNODES * OUTF)      // 1,500,000

// R12 design (rerun; R12 bench was an infra timeout, kernel never ran):
// NO LDS AT ALL. R6-R9 showed the edge kernel pinned at ~28us across
// schedule/occupancy changes -> binding resource is the per-CU LDS pipe
// (3 wave-streams x 240 ds_read_b128 x ~12cyc x 5 blk/CU ~= 14-18us, shared
// by all SIMDs, immune to occupancy). h is wave-uniform -> read it as
// uniform-address global float4 (1 VMEM transaction, L1 broadcast); VMEM
// pipe is ~idle (HBM 6%). Staging loop + both barriers deleted.
__global__ __launch_bounds__(ETHREADS, 4) void edge_msg_kernel(
    const float* __restrict__ feat, const float* __restrict__ efeat,
    const float* __restrict__ W, const float* __restrict__ B,
    const int* __restrict__ src, const int* __restrict__ dst,
    float* __restrict__ sums, float* __restrict__ cnts)
{
    const int tid = threadIdx.x;
    const int kc  = blockIdx.x / NGROUPS;   // consecutive blocks share kc -> W rows L2-hot
    const int grp = blockIdx.x - kc * NGROUPS;
    const int e0  = grp * EPB;
    const int k0  = kc * KCHUNK;

    if (tid < OUTF) {
        // Per-edge 32-bit element offsets (12MB buffer fits 32-bit): keeps
        // addressing as s[feat]+voffset, ~16 VGPRs instead of 16 pointers.
        int off[EPB];
        #pragma unroll
        for (int e = 0; e < EPB; ++e)
            off[e] = src[e0 + e] * INF + k0;

        float accW[EPB], accB[EPB];     // dual acc: each h elem feeds 2 FMAs
        #pragma unroll
        for (int e = 0; e < EPB; ++e) { accW[e] = 0.f; accB[e] = 0.f; }

        const float* Wc = W + (size_t)k0 * OUTF + tid;  // column o = tid
        const float* Bc = B + (size_t)k0 * OUTF + tid;

        #pragma unroll
        for (int ph = 0; ph < PHASES; ++ph) {
            const int base = ph * PROWS;
            float wr[PROWS], br[PROWS];
            #pragma unroll
            for (int r = 0; r < PROWS; ++r) {
                wr[r] = Wc[(size_t)(base + r) * OUTF];   // 24 indep coalesced L2 loads
                br[r] = Bc[(size_t)(base + r) * OUTF];
            }
            __builtin_amdgcn_sched_barrier(0);  // burst stays a burst
            #pragma unroll
            for (int i4 = 0; i4 < PROWS; i4 += 4) {
                #pragma unroll
                for (int e = 0; e < EPB; ++e) {
                    // wave-uniform address -> one 16B fetch, broadcast to lanes
                    const float4 h = *(const float4*)(feat + off[e] + base + i4);
                    accW[e] = fmaf(h.w, wr[i4 + 3], fmaf(h.z, wr[i4 + 2],
                              fmaf(h.y, wr[i4 + 1], fmaf(h.x, wr[i4 + 0], accW[e]))));
                    accB[e] = fmaf(h.w, br[i4 + 3], fmaf(h.z, br[i4 + 2],
                              fmaf(h.y, br[i4 + 1], fmaf(h.x, br[i4 + 0], accB[e]))));
                }
            }
        }
        // epilogue: msg = ef*(h@W) + (h@B), scatter (split-K partials sum via atomics)
        #pragma unroll
        for (int e = 0; e < EPB; ++e) {
            const float msg = fmaf(efeat[e0 + e], accW[e], accB[e]);
            atomicAdd(&sums[(size_t)dst[e0 + e] * OUTF + tid], msg);
        }
    } else if (kc == 0 && tid < OUTF + EPB) {
        atomicAdd(&cnts[dst[e0 + tid - OUTF]], 1.0f);   // each edge counted once
    }
}

__global__ __launch_bounds__(256) void finalize_kernel(
    const float* __restrict__ sums, const float* __restrict__ cnts,
    const float* __restrict__ bias, float* __restrict__ out)
{
    const int idx = blockIdx.x * blockDim.x + threadIdx.x;
    if (idx < SUMS_N) {
        const int n = idx / OUTF;
        const int o = idx - n * OUTF;
        const float c = cnts[n];
        const float m = sums[idx] / fmaxf(c, 1.0f);
        const float v = m + bias[o];
        out[idx] = v > 0.f ? v : 0.f;
    }
}

extern "C" void kernel_launch(void* const* d_in, const int* in_sizes, int n_in,
                              void* d_out, int out_size, void* d_ws, size_t ws_size,
                              hipStream_t stream) {
    const float* feat  = (const float*)d_in[0];
    const float* efeat = (const float*)d_in[1];
    const float* W     = (const float*)d_in[2];
    const float* B     = (const float*)d_in[3];
    const float* bias  = (const float*)d_in[4];
    const int*   src   = (const int*)d_in[5];
    const int*   dst   = (const int*)d_in[6];
    float* out  = (float*)d_out;

    float* sums = (float*)d_ws;                 // [SUMS_N]
    float* cnts = sums + SUMS_N;                // [NNODES]

    hipMemsetAsync(d_ws, 0, (size_t)(SUMS_N + NNODES) * sizeof(float), stream);

    edge_msg_kernel<<<NGROUPS * SPLITK, ETHREADS, 0, stream>>>(
        feat, efeat, W, B, src, dst, sums, cnts);

    finalize_kernel<<<(SUMS_N + 255) / 256, 256, 0, stream>>>(sums, cnts, bias, out);
}